// Round 1
// baseline (90102.393 us; speedup 1.0000x reference)
//
#include <hip/hip_runtime.h>
#include <hip/hip_cooperative_groups.h>

namespace cg = cooperative_groups;

#define T_DIM 512
#define B_DIM 64
#define H_DIM 1024
#define HH ((size_t)H_DIM * H_DIM)

// ws layout (floats):
//   WmT  [6][H][H]   masked-transposed weights: g in {ir,iz,in,hr,hz,hn}, WmT[g][j][k] = (k>=j)?W[k][j]:0
//   hbuf [2][B][H]   hidden ping-pong
//   pmax [T][B][8]   per-column-pair partial maxes of label
// total ~26.7 MB

// ---------------- prep: masked transpose of the 6 weight matrices ----------------
__global__ __launch_bounds__(256) void prep_transpose(
    const float* __restrict__ Wir, const float* __restrict__ Wiz, const float* __restrict__ Win,
    const float* __restrict__ Whr, const float* __restrict__ Whz, const float* __restrict__ Whn,
    float* __restrict__ WmT)
{
    __shared__ float tile[64][65]; // +1 pad: no bank conflicts on transposed read
    const float* srcs[6] = {Wir, Wiz, Win, Whr, Whz, Whn};
    const int g = blockIdx.z;
    const float* src = srcs[g];
    float* dst = WmT + (size_t)g * HH;
    const int j0 = blockIdx.x * 64;
    const int k0 = blockIdx.y * 64;
    const int c = threadIdx.x & 63;
    const int r0 = threadIdx.x >> 6;
    for (int r = r0; r < 64; r += 4)
        tile[r][c] = src[(size_t)(k0 + r) * H_DIM + (j0 + c)];
    __syncthreads();
    for (int r = r0; r < 64; r += 4) {
        const int j = j0 + r;
        const int k = k0 + c;
        const float v = (k >= j) ? tile[c][r] : 0.0f; // tril mask: keep k>=j
        dst[(size_t)j * H_DIM + k] = v;               // coalesced over c=k
    }
}

__global__ __launch_bounds__(256) void init_h(const float* __restrict__ h0, float* __restrict__ hbuf)
{
    const int i = blockIdx.x * 256 + threadIdx.x;
    if (i < B_DIM * H_DIM) hbuf[i] = h0[i];
}

// ---------------- main sequential GRU kernel (cooperative, 1 grid.sync per step) ----------------
// grid = 256 WGs x 512 threads.  WG w: pair p = w&7 owns column blocks {p, 15-p} (64 cols each,
// total k-work 1088 rows -> uniform across pairs); bgrp = w>>3 owns batch rows {2*bgrp, 2*bgrp+1}.
// 8 waves split the k-range of each column block; LDS reduction; wave 0/1 do the pointwise gates.
__global__ __launch_bounds__(512) void gru_main(
    const float* __restrict__ x,      // [T,B,H]
    const float* __restrict__ WmT,    // [6,H,H]
    const float* __restrict__ bir, const float* __restrict__ bhr,
    const float* __restrict__ biz, const float* __restrict__ bhz,
    const float* __restrict__ bin_, const float* __restrict__ bhn,
    const float* __restrict__ Wout, const float* __restrict__ bout,
    float* __restrict__ hbuf,         // [2,B,H]
    float* __restrict__ pmax)         // [T,B,8]
{
    cg::grid_group grid = cg::this_grid();

    __shared__ float sh_x[2][H_DIM];  // x rows b0,b0+1 for current t
    __shared__ float sh_h[2][H_DIM];  // hid rows b0,b0+1
    __shared__ float4 red[8][2][64];  // per-wave partials: (r, z, n_i, n_h)
    __shared__ float mxs[2][2];       // per-b, per-block label max

    const int tid  = threadIdx.x;
    const int lane = tid & 63;
    const int ww   = tid >> 6;
    const int p    = blockIdx.x & 7;
    const int bgrp = blockIdx.x >> 3;
    const int b0   = bgrp * 2;

    const float bo = bout[0];

    for (int t = 0; t < T_DIM; ++t) {
        const float* hid  = hbuf + (size_t)(t & 1) * (B_DIM * H_DIM);
        float*       hidn = hbuf + (size_t)((t + 1) & 1) * (B_DIM * H_DIM);

        // stage x[t] rows b0..b0+1 (contiguous) and hid rows b0..b0+1 (contiguous) into LDS
        {
            const float4* xs = (const float4*)(x + ((size_t)t * B_DIM + b0) * H_DIM);
            const float4* hs = (const float4*)(hid + (size_t)b0 * H_DIM);
            float4* dx = (float4*)sh_x[0];
            float4* dh = (float4*)sh_h[0];
            dx[tid] = xs[tid];   // 512 float4 = 2 rows, exactly one per thread
            dh[tid] = hs[tid];
        }
        __syncthreads();

        for (int blk = 0; blk < 2; ++blk) {
            const int jb   = blk ? (15 - p) : p;
            const int j0   = jb << 6;
            const int j    = j0 + lane;
            const int klen = H_DIM - j0;     // multiple of 64
            const int kcnt = klen >> 3;      // per-wave share, multiple of 8
            const int ks   = j0 + ww * kcnt;

            const float* wir = WmT + (size_t)j * H_DIM;
            const float* wiz = wir + HH;
            const float* win = wir + 2 * HH;
            const float* whr = wir + 3 * HH;
            const float* whz = wir + 4 * HH;
            const float* whn = wir + 5 * HH;

            float4 a0 = make_float4(0.f, 0.f, 0.f, 0.f); // b0: (r, z, n_i, n_h)
            float4 a1 = make_float4(0.f, 0.f, 0.f, 0.f); // b0+1

            #pragma unroll 2
            for (int k = ks; k < ks + kcnt; k += 4) {
                const float4 vir = *(const float4*)(wir + k);
                const float4 viz = *(const float4*)(wiz + k);
                const float4 vin = *(const float4*)(win + k);
                const float4 vhr = *(const float4*)(whr + k);
                const float4 vhz = *(const float4*)(whz + k);
                const float4 vhn = *(const float4*)(whn + k);
                const float4 xv0 = *(const float4*)(&sh_x[0][k]);
                const float4 xv1 = *(const float4*)(&sh_x[1][k]);
                const float4 hv0 = *(const float4*)(&sh_h[0][k]);
                const float4 hv1 = *(const float4*)(&sh_h[1][k]);
#define ACC(q) \
                a0.x = fmaf(xv0.q, vir.q, fmaf(hv0.q, vhr.q, a0.x)); \
                a0.y = fmaf(xv0.q, viz.q, fmaf(hv0.q, vhz.q, a0.y)); \
                a0.z = fmaf(xv0.q, vin.q, a0.z); \
                a0.w = fmaf(hv0.q, vhn.q, a0.w); \
                a1.x = fmaf(xv1.q, vir.q, fmaf(hv1.q, vhr.q, a1.x)); \
                a1.y = fmaf(xv1.q, viz.q, fmaf(hv1.q, vhz.q, a1.y)); \
                a1.z = fmaf(xv1.q, vin.q, a1.z); \
                a1.w = fmaf(hv1.q, vhn.q, a1.w);
                ACC(x) ACC(y) ACC(z) ACC(w)
#undef ACC
            }

            __syncthreads();             // red[] free to overwrite (prev reduction done)
            red[ww][0][lane] = a0;
            red[ww][1][lane] = a1;
            __syncthreads();

            if (tid < 128) {             // waves 0,1: reduce + pointwise for 2 b x 64 j
                const int b  = tid >> 6;
                const int ln = tid & 63;
                const int jj = j0 + ln;
                float4 s = red[0][b][ln];
                #pragma unroll
                for (int w2 = 1; w2 < 8; ++w2) {
                    const float4 v = red[w2][b][ln];
                    s.x += v.x; s.y += v.y; s.z += v.z; s.w += v.w;
                }
                const float xv = sh_x[b][jj];
                const float hv = sh_h[b][jj];
                const float rp = s.x + bir[jj] * xv + bhr[jj];
                const float zp = s.y + biz[jj] * xv + bhz[jj];
                const float r  = 1.0f / (1.0f + expf(-rp));
                const float z  = 1.0f / (1.0f + expf(-zp));
                const float np = s.z + bin_[jj] * xv + r * (s.w + bhn[jj]);
                const float n  = tanhf(np);
                const float hnew = hv * z + (1.0f - z) * n;
                hidn[(size_t)(b0 + b) * H_DIM + jj] = hnew;
                float lab = (1.0f / (1.0f + expf(-(hnew * Wout[jj] + bo)))) * xv;
                #pragma unroll
                for (int off = 32; off; off >>= 1)
                    lab = fmaxf(lab, __shfl_xor(lab, off));
                if (ln == 0) mxs[b][blk] = lab;
            }
        } // blk

        __syncthreads();
        if (tid < 2)
            pmax[((size_t)t * B_DIM + b0 + tid) * 8 + p] = fmaxf(mxs[tid][0], mxs[tid][1]);

        grid.sync(); // hidn visible device-wide before next step reads it
    } // t
}

// ---------------- finalize: reduce 8 partials, threshold, emit int32 ----------------
__global__ __launch_bounds__(256) void finalize(const float* __restrict__ pmax, int* __restrict__ out)
{
    const int i = blockIdx.x * 256 + threadIdx.x; // 0..T*B-1
    if (i >= T_DIM * B_DIM) return;
    const float4* pm = (const float4*)(pmax + (size_t)i * 8);
    const float4 a = pm[0], b = pm[1];
    float m = fmaxf(fmaxf(fmaxf(a.x, a.y), fmaxf(a.z, a.w)),
                    fmaxf(fmaxf(b.x, b.y), fmaxf(b.z, b.w)));
    out[i] = (m >= 0.5f) ? 1 : -1;
}

extern "C" void kernel_launch(void* const* d_in, const int* in_sizes, int n_in,
                              void* d_out, int out_size, void* d_ws, size_t ws_size,
                              hipStream_t stream)
{
    const float* x    = (const float*)d_in[0];
    const float* h0   = (const float*)d_in[1];
    const float* W_ir = (const float*)d_in[2];
    const float* W_hr = (const float*)d_in[3];
    const float* W_iz = (const float*)d_in[4];
    const float* W_hz = (const float*)d_in[5];
    const float* W_in = (const float*)d_in[6];
    const float* W_hn = (const float*)d_in[7];
    const float* b_ir = (const float*)d_in[8];
    const float* b_hr = (const float*)d_in[9];
    const float* b_iz = (const float*)d_in[10];
    const float* b_hz = (const float*)d_in[11];
    const float* b_in = (const float*)d_in[12];
    const float* b_hn = (const float*)d_in[13];
    const float* W_out = (const float*)d_in[14];
    const float* b_out = (const float*)d_in[15];

    float* ws   = (float*)d_ws;
    float* WmT  = ws;                              // 6*HH
    float* hbuf = WmT + 6 * HH;                    // 2*B*H
    float* pmax = hbuf + 2 * (size_t)B_DIM * H_DIM;// T*B*8

    prep_transpose<<<dim3(16, 16, 6), 256, 0, stream>>>(W_ir, W_iz, W_in, W_hr, W_hz, W_hn, WmT);
    init_h<<<dim3(256), 256, 0, stream>>>(h0, hbuf);

    void* args[] = {(void*)&x, (void*)&WmT,
                    (void*)&b_ir, (void*)&b_hr, (void*)&b_iz, (void*)&b_hz,
                    (void*)&b_in, (void*)&b_hn, (void*)&W_out, (void*)&b_out,
                    (void*)&hbuf, (void*)&pmax};
    hipLaunchCooperativeKernel((const void*)gru_main, dim3(256), dim3(512), args, 0, stream);

    finalize<<<dim3(T_DIM * B_DIM / 256), 256, 0, stream>>>(pmax, (int*)d_out);
}

// Round 2
// 26467.258 us; speedup vs baseline: 3.4043x; 3.4043x over previous
//
#include <hip/hip_runtime.h>
#include <hip/hip_cooperative_groups.h>

namespace cg = cooperative_groups;

#define T_DIM 512
#define B_DIM 64
#define H_DIM 1024
#define HH ((size_t)H_DIM * H_DIM)

// ws layout (floats):
//   WmK  [6][H][H]   masked weights in ORIGINAL [k][j] orientation:
//                    WmK[g][k][j] = (k>=j) ? W_g[k][j] : 0   (g in {ir,iz,in,hr,hz,hn})
//   hbuf [2][B][H]   hidden ping-pong
//   pmax [T][B][8]   per-column-pair partial maxes of label
// total ~26.7 MB

// ---------------- prep: mask the 6 weight matrices (no transpose needed) ----------------
__global__ __launch_bounds__(256) void prep_mask(
    const float* __restrict__ Wir, const float* __restrict__ Wiz, const float* __restrict__ Win,
    const float* __restrict__ Whr, const float* __restrict__ Whz, const float* __restrict__ Whn,
    float* __restrict__ WmK)
{
    const float* srcs[6] = {Wir, Wiz, Win, Whr, Whz, Whn};
    const int g = blockIdx.y;
    const int idx = blockIdx.x * 256 + threadIdx.x;   // 0 .. H*H-1
    const int k = idx >> 10;
    const int j = idx & (H_DIM - 1);
    const float v = (k >= j) ? srcs[g][idx] : 0.0f;   // tril: keep k>=j
    WmK[(size_t)g * HH + idx] = v;                    // coalesced
}

__global__ __launch_bounds__(256) void init_h(const float* __restrict__ h0, float* __restrict__ hbuf)
{
    const int i = blockIdx.x * 256 + threadIdx.x;
    if (i < B_DIM * H_DIM) hbuf[i] = h0[i];
}

// ---------------- main sequential GRU kernel (cooperative, 1 grid.sync per step) ----------------
// grid = 256 WGs x 512 threads.  WG w: pair p = w&7 owns column blocks {p, 15-p} (64 cols each,
// total k-work 1088 rows -> uniform across pairs); bgrp = w>>3 owns batch rows {2*bgrp, 2*bgrp+1}.
// Lane <-> column (coalesced weight reads); 8 waves split the k-range; LDS reduction; waves 0/1
// do the pointwise gates.  p = blockIdx&7 also round-robins pairs onto XCDs so each XCD's L2
// holds one pair's 1.67 MB weight stream.
__global__ __launch_bounds__(512) void gru_main(
    const float* __restrict__ x,      // [T,B,H]
    const float* __restrict__ WmK,    // [6,H,H] masked, [k][j]
    const float* __restrict__ bir, const float* __restrict__ bhr,
    const float* __restrict__ biz, const float* __restrict__ bhz,
    const float* __restrict__ bin_, const float* __restrict__ bhn,
    const float* __restrict__ Wout, const float* __restrict__ bout,
    float* __restrict__ hbuf,         // [2,B,H]
    float* __restrict__ pmax)         // [T,B,8]
{
    cg::grid_group grid = cg::this_grid();

    __shared__ float sh_x[2][H_DIM];  // x rows b0,b0+1 for current t
    __shared__ float sh_h[2][H_DIM];  // hid rows b0,b0+1
    __shared__ float4 red[8][2][64];  // per-wave partials: (r, z, n_i, n_h)
    __shared__ float mxs[2][2];       // per-b, per-block label max

    const int tid  = threadIdx.x;
    const int lane = tid & 63;
    const int ww   = tid >> 6;
    const int p    = blockIdx.x & 7;
    const int bgrp = blockIdx.x >> 3;
    const int b0   = bgrp * 2;

    const float bo = bout[0];

    for (int t = 0; t < T_DIM; ++t) {
        const float* hid  = hbuf + (size_t)(t & 1) * (B_DIM * H_DIM);
        float*       hidn = hbuf + (size_t)((t + 1) & 1) * (B_DIM * H_DIM);

        // stage x[t] rows b0..b0+1 (contiguous) and hid rows b0..b0+1 (contiguous) into LDS
        {
            const float4* xs = (const float4*)(x + ((size_t)t * B_DIM + b0) * H_DIM);
            const float4* hs = (const float4*)(hid + (size_t)b0 * H_DIM);
            float4* dx = (float4*)sh_x[0];
            float4* dh = (float4*)sh_h[0];
            dx[tid] = xs[tid];   // 512 float4 = 2 rows, exactly one per thread
            dh[tid] = hs[tid];
        }
        __syncthreads();

        for (int blk = 0; blk < 2; ++blk) {
            const int jb   = blk ? (15 - p) : p;
            const int j0   = jb << 6;
            const int j    = j0 + lane;
            const int klen = H_DIM - j0;     // multiple of 64
            const int kcnt = klen >> 3;      // per-wave share (k rows), multiple of 8
            const int ks   = j0 + ww * kcnt;

            // lane <-> column j; per k the wave reads 256B contiguous per gate
            const float* wir = WmK + j;
            const float* wiz = wir + HH;
            const float* win = wir + 2 * HH;
            const float* whr = wir + 3 * HH;
            const float* whz = wir + 4 * HH;
            const float* whn = wir + 5 * HH;

            float4 a0 = make_float4(0.f, 0.f, 0.f, 0.f); // b0: (r, z, n_i, n_h)
            float4 a1 = make_float4(0.f, 0.f, 0.f, 0.f); // b0+1

            #pragma unroll 4
            for (int k = ks; k < ks + kcnt; ++k) {
                const size_t off = (size_t)k << 10;     // k * H
                const float vir = wir[off];
                const float viz = wiz[off];
                const float vin = win[off];
                const float vhr = whr[off];
                const float vhz = whz[off];
                const float vhn = whn[off];
                const float xv0 = sh_x[0][k];           // broadcast
                const float xv1 = sh_x[1][k];
                const float hv0 = sh_h[0][k];
                const float hv1 = sh_h[1][k];
                a0.x = fmaf(xv0, vir, fmaf(hv0, vhr, a0.x));
                a0.y = fmaf(xv0, viz, fmaf(hv0, vhz, a0.y));
                a0.z = fmaf(xv0, vin, a0.z);
                a0.w = fmaf(hv0, vhn, a0.w);
                a1.x = fmaf(xv1, vir, fmaf(hv1, vhr, a1.x));
                a1.y = fmaf(xv1, viz, fmaf(hv1, vhz, a1.y));
                a1.z = fmaf(xv1, vin, a1.z);
                a1.w = fmaf(hv1, vhn, a1.w);
            }

            __syncthreads();             // red[] free to overwrite (prev reduction done)
            red[ww][0][lane] = a0;
            red[ww][1][lane] = a1;
            __syncthreads();

            if (tid < 128) {             // waves 0,1: reduce + pointwise for 2 b x 64 j
                const int b  = tid >> 6;
                const int ln = tid & 63;
                const int jj = j0 + ln;
                float4 s = red[0][b][ln];
                #pragma unroll
                for (int w2 = 1; w2 < 8; ++w2) {
                    const float4 v = red[w2][b][ln];
                    s.x += v.x; s.y += v.y; s.z += v.z; s.w += v.w;
                }
                const float xv = sh_x[b][jj];
                const float hv = sh_h[b][jj];
                const float rp = s.x + bir[jj] * xv + bhr[jj];
                const float zp = s.y + biz[jj] * xv + bhz[jj];
                const float r  = 1.0f / (1.0f + expf(-rp));
                const float z  = 1.0f / (1.0f + expf(-zp));
                const float np = s.z + bin_[jj] * xv + r * (s.w + bhn[jj]);
                const float n  = tanhf(np);
                const float hnew = hv * z + (1.0f - z) * n;
                hidn[(size_t)(b0 + b) * H_DIM + jj] = hnew;
                float lab = (1.0f / (1.0f + expf(-(hnew * Wout[jj] + bo)))) * xv;
                #pragma unroll
                for (int off = 32; off; off >>= 1)
                    lab = fmaxf(lab, __shfl_xor(lab, off));
                if (ln == 0) mxs[b][blk] = lab;
            }
        } // blk

        __syncthreads();
        if (tid < 2)
            pmax[((size_t)t * B_DIM + b0 + tid) * 8 + p] = fmaxf(mxs[tid][0], mxs[tid][1]);

        grid.sync(); // hidn visible device-wide before next step reads it
    } // t
}

// ---------------- finalize: reduce 8 partials, threshold, emit int32 ----------------
__global__ __launch_bounds__(256) void finalize(const float* __restrict__ pmax, int* __restrict__ out)
{
    const int i = blockIdx.x * 256 + threadIdx.x; // 0..T*B-1
    if (i >= T_DIM * B_DIM) return;
    const float4* pm = (const float4*)(pmax + (size_t)i * 8);
    const float4 a = pm[0], b = pm[1];
    float m = fmaxf(fmaxf(fmaxf(a.x, a.y), fmaxf(a.z, a.w)),
                    fmaxf(fmaxf(b.x, b.y), fmaxf(b.z, b.w)));
    out[i] = (m >= 0.5f) ? 1 : -1;
}

extern "C" void kernel_launch(void* const* d_in, const int* in_sizes, int n_in,
                              void* d_out, int out_size, void* d_ws, size_t ws_size,
                              hipStream_t stream)
{
    const float* x    = (const float*)d_in[0];
    const float* h0   = (const float*)d_in[1];
    const float* W_ir = (const float*)d_in[2];
    const float* W_hr = (const float*)d_in[3];
    const float* W_iz = (const float*)d_in[4];
    const float* W_hz = (const float*)d_in[5];
    const float* W_in = (const float*)d_in[6];
    const float* W_hn = (const float*)d_in[7];
    const float* b_ir = (const float*)d_in[8];
    const float* b_hr = (const float*)d_in[9];
    const float* b_iz = (const float*)d_in[10];
    const float* b_hz = (const float*)d_in[11];
    const float* b_in = (const float*)d_in[12];
    const float* b_hn = (const float*)d_in[13];
    const float* W_out = (const float*)d_in[14];
    const float* b_out = (const float*)d_in[15];

    float* ws   = (float*)d_ws;
    float* WmK  = ws;                              // 6*HH
    float* hbuf = WmK + 6 * HH;                    // 2*B*H
    float* pmax = hbuf + 2 * (size_t)B_DIM * H_DIM;// T*B*8

    prep_mask<<<dim3(H_DIM * H_DIM / 256, 6), 256, 0, stream>>>(W_ir, W_iz, W_in, W_hr, W_hz, W_hn, WmK);
    init_h<<<dim3(256), 256, 0, stream>>>(h0, hbuf);

    void* args[] = {(void*)&x, (void*)&WmK,
                    (void*)&b_ir, (void*)&b_hr, (void*)&b_iz, (void*)&b_hz,
                    (void*)&b_in, (void*)&b_hn, (void*)&W_out, (void*)&b_out,
                    (void*)&hbuf, (void*)&pmax};
    hipLaunchCooperativeKernel((const void*)gru_main, dim3(256), dim3(512), args, 0, stream);

    finalize<<<dim3(T_DIM * B_DIM / 256), 256, 0, stream>>>(pmax, (int*)d_out);
}